// Round 5
// baseline (225.959 us; speedup 1.0000x reference)
//
#include <hip/hip_runtime.h>
#include <math.h>

// GraphLaplacian: out[b,v] = || sum_w L[v,w] * verts[b,w,:] ||_2
// L is 6000x6000 fp32, ~13 nnz/row. Three decoupled dispatches:
//  1) zero per-row counters in ws
//  2) scan_compact: pure grid-strided stream of L (no barriers, 8 loads in
//     flight per thread) -> per-row CSR lists in ws (global atomics, ~78K total)
//  3) spmm_norm: per-row gather against L2-resident verts + sqrt-norm.
// Decoupling keeps the 144 MB scan at fill-kernel BW instead of stalling at
// per-block gather barriers.

#define NUM_V   6000
#define BATCH   32
#define ROW_F4  1500
#define TOT_F4  (NUM_V * ROW_F4)     // 2,250,000 float4 = 144 MB
#define SLOTS   64                   // max row degree ~45 incl diagonal
#define SCAN_BPT 8                   // float4 per thread
#define SCAN_CHUNK (256 * SCAN_BPT)  // 2048 float4 per block
#define SCAN_BLOCKS ((TOT_F4 + SCAN_CHUNK - 1) / SCAN_CHUNK)   // 1099

// ws layout (bytes):
#define WS_CNT_OFF   0                         // int cnt[NUM_V]
#define WS_COLS_OFF  32768                     // int cols[NUM_V*SLOTS]
#define WS_VALS_OFF  (32768 + NUM_V*SLOTS*4)   // float vals[NUM_V*SLOTS]

__global__ void zero_cnt_kernel(int* __restrict__ cnt) {
    const int i = blockIdx.x * 256 + threadIdx.x;
    if (i < NUM_V) cnt[i] = 0;
}

__global__ __launch_bounds__(256, 4)
void scan_compact_kernel(const float* __restrict__ L,
                         int* __restrict__ cnt,
                         int* __restrict__ cols,
                         float* __restrict__ vals) {
    const float4* Lf = reinterpret_cast<const float4*>(L);
    const int base = blockIdx.x * SCAN_CHUNK + threadIdx.x;

    // issue all 8 independent, coalesced loads up front
    float4 q[SCAN_BPT];
    int    f[SCAN_BPT];
    #pragma unroll
    for (int j = 0; j < SCAN_BPT; ++j) {
        f[j] = base + j * 256;
        q[j] = (f[j] < TOT_F4) ? Lf[f[j]] : make_float4(0.f, 0.f, 0.f, 0.f);
    }

    #pragma unroll
    for (int j = 0; j < SCAN_BPT; ++j) {
        const float4 a = q[j];
        if ((a.x != 0.f) | (a.y != 0.f) | (a.z != 0.f) | (a.w != 0.f)) {
            const int v  = f[j] / 1500;             // row
            const int c0 = (f[j] - v * 1500) * 4;   // starting col
            if (a.x != 0.f) { int p = atomicAdd(&cnt[v], 1); if (p < SLOTS) { cols[v*SLOTS+p] = c0;     vals[v*SLOTS+p] = a.x; } }
            if (a.y != 0.f) { int p = atomicAdd(&cnt[v], 1); if (p < SLOTS) { cols[v*SLOTS+p] = c0 + 1; vals[v*SLOTS+p] = a.y; } }
            if (a.z != 0.f) { int p = atomicAdd(&cnt[v], 1); if (p < SLOTS) { cols[v*SLOTS+p] = c0 + 2; vals[v*SLOTS+p] = a.z; } }
            if (a.w != 0.f) { int p = atomicAdd(&cnt[v], 1); if (p < SLOTS) { cols[v*SLOTS+p] = c0 + 3; vals[v*SLOTS+p] = a.w; } }
        }
    }
}

__global__ __launch_bounds__(128, 8)
void spmm_norm_kernel(const float* __restrict__ verts,
                      const int* __restrict__ cnt,
                      const int* __restrict__ cols,
                      const float* __restrict__ vals,
                      float* __restrict__ out) {
    __shared__ int   s_c[SLOTS];
    __shared__ float s_v[SLOTS];
    __shared__ float s_part[96];

    const int v = blockIdx.x;
    const int t = threadIdx.x;
    const int c = min(max(cnt[v], 0), SLOTS);

    if (t < SLOTS && t < c) {
        s_c[t] = cols[v * SLOTS + t];
        s_v[t] = vals[v * SLOTS + t];
    }
    __syncthreads();

    if (t < BATCH * 3) {
        const int b = t / 3;
        const int d = t - 3 * b;
        const float* vb = verts + (size_t)b * (NUM_V * 3) + d;
        float acc = 0.f;
        for (int i = 0; i < c; ++i)
            acc = fmaf(s_v[i], vb[(size_t)s_c[i] * 3], acc);   // LDS broadcast + L2 gather
        s_part[t] = acc;
    }
    __syncthreads();

    if (t < BATCH) {
        const float x = s_part[3 * t + 0];
        const float y = s_part[3 * t + 1];
        const float z = s_part[3 * t + 2];
        out[(size_t)t * NUM_V + v] = sqrtf(fmaf(x, x, fmaf(y, y, z * z)));
    }
}

extern "C" void kernel_launch(void* const* d_in, const int* in_sizes, int n_in,
                              void* d_out, int out_size, void* d_ws, size_t ws_size,
                              hipStream_t stream) {
    const float* verts = (const float*)d_in[0];   // (32, 6000, 3) fp32
    const float* L     = (const float*)d_in[1];   // (6000, 6000) fp32
    float* out         = (float*)d_out;           // (32, 6000)  fp32

    char* ws = (char*)d_ws;
    int*   cnt  = (int*)  (ws + WS_CNT_OFF);
    int*   cols = (int*)  (ws + WS_COLS_OFF);
    float* vals = (float*)(ws + WS_VALS_OFF);

    zero_cnt_kernel<<<(NUM_V + 255) / 256, 256, 0, stream>>>(cnt);
    scan_compact_kernel<<<SCAN_BLOCKS, 256, 0, stream>>>(L, cnt, cols, vals);
    spmm_norm_kernel<<<NUM_V, 128, 0, stream>>>(verts, cnt, cols, vals, out);
}

// Round 6
// 209.617 us; speedup vs baseline: 1.0780x; 1.0780x over previous
//
#include <hip/hip_runtime.h>
#include <math.h>

// GraphLaplacian: out[b,v] = || sum_w L[v,w] * verts[b,w,:] ||_2
// L is 6000x6000 fp32, ~13 nnz/row. One block per row, single dispatch
// (fastest measured variant: R3, 209.3 us).
// Phase 1: stream the row with 6 float4 loads/thread all in flight.
// Phase 2: nnz gather with 2 threads per (b,d) pair + 4-wide unroll so
//          gathers overlap instead of forming a latency chain.
// Kernel contribution ~25-35 us vs a 23 us mandatory-read floor (144 MB of L
// restored pristine before every launch); remaining ~180 us of dur_us is
// harness reset traffic (576 MB ws poison @ 85 us measured + L restore +
// tiny reset dispatches) — not touchable from kernel code.

#define NUM_V   6000
#define BATCH   32
#define ROW_F4  (NUM_V / 4)     // 1500 float4 per row
#define MAX_NNZ 256             // max row degree ~35; big margin

__device__ __forceinline__ void collect(float4 a, int c0,
                                        int* s_cols, float* s_vals, int* s_cnt) {
    bool nz = (a.x != 0.f) | (a.y != 0.f) | (a.z != 0.f) | (a.w != 0.f);
    if (nz) {
        if (a.x != 0.f) { int p = atomicAdd(s_cnt, 1); s_cols[p] = c0;     s_vals[p] = a.x; }
        if (a.y != 0.f) { int p = atomicAdd(s_cnt, 1); s_cols[p] = c0 + 1; s_vals[p] = a.y; }
        if (a.z != 0.f) { int p = atomicAdd(s_cnt, 1); s_cols[p] = c0 + 2; s_vals[p] = a.z; }
        if (a.w != 0.f) { int p = atomicAdd(s_cnt, 1); s_cols[p] = c0 + 3; s_vals[p] = a.w; }
    }
}

__global__ __launch_bounds__(256, 8)
void graph_laplacian_kernel(const float* __restrict__ verts,
                            const float* __restrict__ L,
                            float* __restrict__ out) {
    __shared__ int   s_cols[MAX_NNZ];
    __shared__ float s_vals[MAX_NNZ];
    __shared__ int   s_cnt;
    __shared__ float s_part[192];

    const int v = blockIdx.x;
    const int t = threadIdx.x;

    if (t == 0) s_cnt = 0;

    // ---- Phase 1: issue all 6 row loads up front (stride-256, coalesced) ----
    const float4* rowp = reinterpret_cast<const float4*>(L + (size_t)v * NUM_V);
    float4 a0 = rowp[t];
    float4 a1 = rowp[t + 256];
    float4 a2 = rowp[t + 512];
    float4 a3 = rowp[t + 768];
    float4 a4 = rowp[t + 1024];
    float4 a5 = (t < ROW_F4 - 1280) ? rowp[t + 1280] : make_float4(0.f, 0.f, 0.f, 0.f);

    __syncthreads();   // s_cnt=0 visible; overlaps with load latency

    collect(a0, 4 * t,            s_cols, s_vals, &s_cnt);
    collect(a1, 4 * (t + 256),    s_cols, s_vals, &s_cnt);
    collect(a2, 4 * (t + 512),    s_cols, s_vals, &s_cnt);
    collect(a3, 4 * (t + 768),    s_cols, s_vals, &s_cnt);
    collect(a4, 4 * (t + 1024),   s_cols, s_vals, &s_cnt);
    collect(a5, 4 * (t + 1280),   s_cols, s_vals, &s_cnt);
    __syncthreads();

    int cnt = s_cnt;
    if (cnt > MAX_NNZ) cnt = MAX_NNZ;   // safety clamp (never hit for this input)

    // ---- Phase 2: 192 threads = 2 per (batch,dim) pair, 4-wide unrolled ----
    if (t < 192) {
        const int p = t >> 1;           // pair 0..95
        const int h = t & 1;            // half 0/1
        const int b = p / 3;
        const int d = p - 3 * b;
        const float* vb = verts + (size_t)b * (NUM_V * 3) + d;
        float acc = 0.f;
        int i = h;
        for (; i + 6 < cnt; i += 8) {
            int   c0 = s_cols[i],     c1 = s_cols[i + 2],
                  c2 = s_cols[i + 4], c3 = s_cols[i + 6];
            float w0 = s_vals[i],     w1 = s_vals[i + 2],
                  w2 = s_vals[i + 4], w3 = s_vals[i + 6];
            float x0 = vb[c0 * 3], x1 = vb[c1 * 3], x2 = vb[c2 * 3], x3 = vb[c3 * 3];
            acc = fmaf(w0, x0, fmaf(w1, x1, fmaf(w2, x2, fmaf(w3, x3, acc))));
        }
        for (; i < cnt; i += 2)
            acc = fmaf(s_vals[i], vb[(size_t)s_cols[i] * 3], acc);
        s_part[t] = acc;
    }
    __syncthreads();

    // ---- Phase 3: combine halves + dims, write norm ----
    if (t < BATCH) {
        float x = s_part[6 * t + 0] + s_part[6 * t + 1];
        float y = s_part[6 * t + 2] + s_part[6 * t + 3];
        float z = s_part[6 * t + 4] + s_part[6 * t + 5];
        out[(size_t)t * NUM_V + v] = sqrtf(fmaf(x, x, fmaf(y, y, z * z)));
    }
}

extern "C" void kernel_launch(void* const* d_in, const int* in_sizes, int n_in,
                              void* d_out, int out_size, void* d_ws, size_t ws_size,
                              hipStream_t stream) {
    const float* verts = (const float*)d_in[0];   // (32, 6000, 3) fp32
    const float* L     = (const float*)d_in[1];   // (6000, 6000) fp32
    float* out         = (float*)d_out;           // (32, 6000)  fp32

    graph_laplacian_kernel<<<NUM_V, 256, 0, stream>>>(verts, L, out);
}